// Round 7
// baseline (164.881 us; speedup 1.0000x reference)
//
#include <hip/hip_runtime.h>
#include <hip/hip_bf16.h>

// LFQ argmax, round 21: r20 + anti-lockstep phase stagger.
// r20 forensics: counted vmcnt landed clean (FETCH 35MB, VGPR 124, no
// spill) and changed NOTHING -> drain theory falsified. Re-derivation:
// per SIMD per tile, MFMA 2480 + screen-VALU 1024 + DS ~500 + bubbles
// ~400 = 3900 cyc = measured elapsed -> pipes run as the SUM, zero
// overlap. The two waves sharing each SIMD belong to the two co-resident
// blocks, which start together, run identical code, barrier at identical
// cadence -> phase LOCKSTEP: both MFMA together (pipe serializes), both
// screen together (VALU serializes). Explains r16's null too (4 blocks,
// still lockstep). Fix: one-time ~1920-cycle s_sleep for one block of
// each co-resident pair ((blockIdx>>8)&1 under round-robin XCD dispatch:
// pairs are (b, b+256)), injected after its prefetch is issued. Offsets
// persist (equal per-tile rates); anti-phase is self-stable (offset block
// runs MFMA uncontended). Everything else byte-identical to r20.
// Numerics unchanged (validated r15-r20): 1-term bf16 screen, 7-bit
// j-pack top-2 per split, MARGIN 0.4 exact rescore.
#define NT 16384
#define ND 128
#define NC 16384
#define NSPLIT 8
#define MARGIN 0.4f       // >= 3x worst pairwise 1-term bf16 comparison error
#define TILE_BYTES 16384  // 64 codes x 128 dims x 2B (hi only)
#define NTILES 32         // tiles per 2048-code slice

typedef __bf16 bf16x8 __attribute__((ext_vector_type(8)));
typedef unsigned short u16x8 __attribute__((ext_vector_type(8)));
typedef float f32x4 __attribute__((ext_vector_type(4)));

#define MF __builtin_amdgcn_mfma_f32_16x16x32_bf16

static __device__ __forceinline__ unsigned short f2bf(float f) {
    unsigned u = __float_as_uint(f);
    return (unsigned short)((u + 0x7FFFu + ((u >> 16) & 1u)) >> 16);
}
static __device__ __forceinline__ float bf2f(unsigned short u) {
    return __uint_as_float(((unsigned)u) << 16);
}
static __device__ __forceinline__ bf16x8 u2b(u16x8 u) {
    return __builtin_bit_cast(bf16x8, u);
}
static __device__ __forceinline__ void gl2lds(const void* g, void* l) {
    __builtin_amdgcn_global_load_lds(
        (const __attribute__((address_space(1))) unsigned int*)g,
        (__attribute__((address_space(3))) unsigned int*)l, 16, 0, 0);
}

// ---- codebook fp32 -> bf16 hi, 64-code tile images w/ chunk rotation ----
// Tile t: u16 span [t*8192, t*8192+8192).
// Element (code c, dim d): r=c&63, pos=((d>>3)+r)&15 ->
//   t*8192 + r*128 + pos*8 + (d&7).
// One thread per (code, 8-dim chunk): 32B contiguous read, 16B store.
__global__ __launch_bounds__(256) void lfq_convert_cb(
    const float4* __restrict__ cb4, unsigned short* __restrict__ cbs)
{
    const unsigned i = blockIdx.x * 256 + threadIdx.x;   // 0..262143
    const unsigned c = i >> 4;           // code
    const unsigned k = i & 15u;          // dim chunk (d0 = k*8)
    const float4 v0 = cb4[i * 2];
    const float4 v1 = cb4[i * 2 + 1];
    const unsigned tile = c >> 6, r = c & 63u;
    const unsigned pos  = (k + r) & 15u;
    u16x8 h;
    h[0] = f2bf(v0.x); h[1] = f2bf(v0.y); h[2] = f2bf(v0.z); h[3] = f2bf(v0.w);
    h[4] = f2bf(v1.x); h[5] = f2bf(v1.y); h[6] = f2bf(v1.z); h[7] = f2bf(v1.w);
    *(u16x8*)(cbs + tile * 8192u + r * 128u + pos * 8u) = h;
}

// exact fp32 dot, register-preloaded x (fallback kernel)
static __device__ __forceinline__ float exact_dot(
    const float4* __restrict__ xr4, const float* __restrict__ cf, int cidx)
{
    const float4* cr = (const float4*)(cf + (size_t)cidx * ND);
    float a0 = 0.f, a1 = 0.f, a2 = 0.f, a3 = 0.f;
#pragma unroll
    for (int i = 0; i < 32; i += 4) {
        float4 x0 = xr4[i+0], x1 = xr4[i+1], x2 = xr4[i+2], x3 = xr4[i+3];
        float4 c0 = cr[i+0],  c1 = cr[i+1],  c2 = cr[i+2],  c3 = cr[i+3];
        a0 += x0.x*c0.x + x0.y*c0.y + x0.z*c0.z + x0.w*c0.w;
        a1 += x1.x*c1.x + x1.y*c1.y + x1.z*c1.z + x1.w*c1.w;
        a2 += x2.x*c2.x + x2.y*c2.y + x2.z*c2.z + x2.w*c2.w;
        a3 += x3.x*c3.x + x3.y*c3.y + x3.z*c3.z + x3.w*c3.w;
    }
    return (a0 + a1) + (a2 + a3);
}

// exact fp32 dot, both operands from global (combine kernel; identical
// summation order to exact_dot -> deterministic across call sites)
static __device__ __forceinline__ float exact_dot_g(
    const float* __restrict__ xf, const float* __restrict__ cf,
    int token, int cidx)
{
    const float4* xr = (const float4*)(xf + (size_t)token * ND);
    const float4* cr = (const float4*)(cf + (size_t)cidx * ND);
    float a0 = 0.f, a1 = 0.f, a2 = 0.f, a3 = 0.f;
#pragma unroll
    for (int i = 0; i < 32; i += 4) {
        float4 x0 = xr[i+0], x1 = xr[i+1], x2 = xr[i+2], x3 = xr[i+3];
        float4 c0 = cr[i+0], c1 = cr[i+1], c2 = cr[i+2], c3 = cr[i+3];
        a0 += x0.x*c0.x + x0.y*c0.y + x0.z*c0.z + x0.w*c0.w;
        a1 += x1.x*c1.x + x1.y*c1.y + x1.z*c1.z + x1.w*c1.w;
        a2 += x2.x*c2.x + x2.y*c2.y + x2.z*c2.z + x2.w*c2.w;
        a3 += x3.x*c3.x + x3.y*c3.y + x3.z*c3.z + x3.w*c3.w;
    }
    return (a0 + a1) + (a2 + a3);
}

static __device__ __forceinline__ void top2_upd(
    const f32x4& a, float* b1r, float* b2r, unsigned pk)
{
#pragma unroll
    for (int r4 = 0; r4 < 4; ++r4) {
        float p = __uint_as_float((__float_as_uint(a[r4]) & 0xFFFFFF80u) | pk);
        b2r[r4] = __builtin_amdgcn_fmed3f(p, b1r[r4], b2r[r4]);
        b1r[r4] = fmaxf(p, b1r[r4]);
    }
}

// ---- stage 1: grid 512 = 64 token-blocks(256 tok) x 8 splits ----
// Block: 256 threads = 4 waves; wave w covers tokens t0+w*64..+63 (tt=4),
// all waves sweep the 2048-code slice from LDS (64-code hi-only tiles,
// 3-buffer rotation, counted-vmcnt pipeline, anti-lockstep stagger).
__global__ __launch_bounds__(256)
__attribute__((amdgpu_waves_per_eu(2, 2)))
void lfq_stage1(
    const float* __restrict__ xf, const unsigned short* __restrict__ cbs,
    float* __restrict__ sb1, float* __restrict__ sb2,
    int* __restrict__ si1, int* __restrict__ si2)
{
    const int split = blockIdx.x & 7;
    const int tb    = blockIdx.x >> 3;
    const int t0    = tb * 256;
    const int tid   = threadIdx.x;
    const int w     = tid >> 6;       // wave id = token-group, 0..3
    const int lane  = tid & 63;
    const int n     = lane & 15;
    const int quad  = lane >> 4;

    __shared__ __attribute__((aligned(16))) unsigned char lds[3 * TILE_BYTES];

    // A fragments: tokens t0 + w*64 + tt*16 + n, tt=0..3; fp32 -> bf16 (RN).
    bf16x8 ah[4][4];
#pragma unroll
    for (int tt = 0; tt < 4; ++tt) {
        const float* xr = xf + (size_t)(t0 + w * 64 + tt * 16 + n) * ND + quad * 8;
#pragma unroll
        for (int kk = 0; kk < 4; ++kk) {
            float4 v0 = *(const float4*)(xr + kk * 32);
            float4 v1 = *(const float4*)(xr + kk * 32 + 4);
            u16x8 hu;
            hu[0] = f2bf(v0.x);
            hu[1] = f2bf(v0.y);
            hu[2] = f2bf(v0.z);
            hu[3] = f2bf(v0.w);
            hu[4] = f2bf(v1.x);
            hu[5] = f2bf(v1.y);
            hu[6] = f2bf(v1.z);
            hu[7] = f2bf(v1.w);
            ah[tt][kk] = u2b(hu);
        }
    }

    float b1[4][4], b2[4][4];
#pragma unroll
    for (int tt = 0; tt < 4; ++tt)
#pragma unroll
        for (int r = 0; r < 4; ++r) { b1[tt][r] = -3.0e38f; b2[tt][r] = -3.0e38f; }

    const unsigned char* gtiles =
        (const unsigned char*)cbs + (size_t)(split * NTILES) * TILE_BYTES;
    const unsigned sgo  = (unsigned)(tid * 16);   // global per-lane (contiguous)
    const unsigned ldso = (unsigned)(w * 1024);   // wave-uniform LDS segment

    // per-lane B-fragment byte offsets within a 16-code subset (s-invariant:
    // row r = s*16+n -> rotation (quad+r)&15 == (quad+n)&15)
    const unsigned bb0 = (unsigned)n * 256u + ((((unsigned)(quad + n     )) & 15u) << 4);
    const unsigned bb1 = (unsigned)n * 256u + ((((unsigned)(quad + n +  4)) & 15u) << 4);
    const unsigned bb2 = (unsigned)n * 256u + ((((unsigned)(quad + n +  8)) & 15u) << 4);
    const unsigned bb3 = (unsigned)n * 256u + ((((unsigned)(quad + n + 12)) & 15u) << 4);

    // pinned zero quad: MFMA C-input for the first K-step of every chain
    const f32x4 zq = {0.f, 0.f, 0.f, 0.f};

    // One subset-PAIR: 8 ds_read_b128, 32 MFMAs over 8 chains
    // (4 token-groups x 2 subsets), then 8 top-2 screens.
#define PAIR(BUFO, SOFF, PKBASE)                                               \
    {                                                                          \
        bf16x8 qa0 = *(const bf16x8*)&lds[(BUFO) + (SOFF)          + bb0];     \
        bf16x8 qa1 = *(const bf16x8*)&lds[(BUFO) + (SOFF)          + bb1];     \
        bf16x8 qa2 = *(const bf16x8*)&lds[(BUFO) + (SOFF)          + bb2];     \
        bf16x8 qa3 = *(const bf16x8*)&lds[(BUFO) + (SOFF)          + bb3];     \
        bf16x8 qb0 = *(const bf16x8*)&lds[(BUFO) + (SOFF) + 4096u  + bb0];     \
        bf16x8 qb1 = *(const bf16x8*)&lds[(BUFO) + (SOFF) + 4096u  + bb1];     \
        bf16x8 qb2 = *(const bf16x8*)&lds[(BUFO) + (SOFF) + 4096u  + bb2];     \
        bf16x8 qb3 = *(const bf16x8*)&lds[(BUFO) + (SOFF) + 4096u  + bb3];     \
        f32x4 aA0, aA1, aA2, aA3, aB0, aB1, aB2, aB3;                          \
        __builtin_amdgcn_s_setprio(1);                                         \
        aA0 = MF(ah[0][0], qa0, zq,  0,0,0);                                   \
        aA1 = MF(ah[1][0], qa0, zq,  0,0,0);                                   \
        aA2 = MF(ah[2][0], qa0, zq,  0,0,0);                                   \
        aA3 = MF(ah[3][0], qa0, zq,  0,0,0);                                   \
        aB0 = MF(ah[0][0], qb0, zq,  0,0,0);                                   \
        aB1 = MF(ah[1][0], qb0, zq,  0,0,0);                                   \
        aB2 = MF(ah[2][0], qb0, zq,  0,0,0);                                   \
        aB3 = MF(ah[3][0], qb0, zq,  0,0,0);                                   \
        aA0 = MF(ah[0][1], qa1, aA0, 0,0,0);                                   \
        aA1 = MF(ah[1][1], qa1, aA1, 0,0,0);                                   \
        aA2 = MF(ah[2][1], qa1, aA2, 0,0,0);                                   \
        aA3 = MF(ah[3][1], qa1, aA3, 0,0,0);                                   \
        aB0 = MF(ah[0][1], qb1, aB0, 0,0,0);                                   \
        aB1 = MF(ah[1][1], qb1, aB1, 0,0,0);                                   \
        aB2 = MF(ah[2][1], qb1, aB2, 0,0,0);                                   \
        aB3 = MF(ah[3][1], qb1, aB3, 0,0,0);                                   \
        aA0 = MF(ah[0][2], qa2, aA0, 0,0,0);                                   \
        aA1 = MF(ah[1][2], qa2, aA1, 0,0,0);                                   \
        aA2 = MF(ah[2][2], qa2, aA2, 0,0,0);                                   \
        aA3 = MF(ah[3][2], qa2, aA3, 0,0,0);                                   \
        aB0 = MF(ah[0][2], qb2, aB0, 0,0,0);                                   \
        aB1 = MF(ah[1][2], qb2, aB1, 0,0,0);                                   \
        aB2 = MF(ah[2][2], qb2, aB2, 0,0,0);                                   \
        aB3 = MF(ah[3][2], qb2, aB3, 0,0,0);                                   \
        aA0 = MF(ah[0][3], qa3, aA0, 0,0,0);                                   \
        aA1 = MF(ah[1][3], qa3, aA1, 0,0,0);                                   \
        aA2 = MF(ah[2][3], qa3, aA2, 0,0,0);                                   \
        aA3 = MF(ah[3][3], qa3, aA3, 0,0,0);                                   \
        aB0 = MF(ah[0][3], qb3, aB0, 0,0,0);                                   \
        aB1 = MF(ah[1][3], qb3, aB1, 0,0,0);                                   \
        aB2 = MF(ah[2][3], qb3, aB2, 0,0,0);                                   \
        aB3 = MF(ah[3][3], qb3, aB3, 0,0,0);                                   \
        __builtin_amdgcn_s_setprio(0);                                         \
        const unsigned pkA = (unsigned)(127 - (PKBASE));                       \
        const unsigned pkB = (unsigned)(127 - ((PKBASE) + 1));                 \
        top2_upd(aA0, b1[0], b2[0], pkA);                                      \
        top2_upd(aA1, b1[1], b2[1], pkA);                                      \
        top2_upd(aA2, b1[2], b2[2], pkA);                                      \
        top2_upd(aA3, b1[3], b2[3], pkA);                                      \
        top2_upd(aB0, b1[0], b2[0], pkB);                                      \
        top2_upd(aB1, b1[1], b2[1], pkB);                                      \
        top2_upd(aB2, b1[2], b2[2], pkB);                                      \
        top2_upd(aB3, b1[3], b2[3], pkB);                                      \
    }

    // stage tile TT (4 x 4KB rounds) into LDS buffer at byte offset NBO
#define STAGE(TT, NBO)                                                         \
    {                                                                          \
        const unsigned char* g = gtiles + (size_t)(TT) * TILE_BYTES;           \
        gl2lds(g +     0 + sgo, &lds[(NBO)          + ldso]);                  \
        gl2lds(g +  4096 + sgo, &lds[(NBO) +  4096u + ldso]);                  \
        gl2lds(g +  8192 + sgo, &lds[(NBO) +  8192u + ldso]);                  \
        gl2lds(g + 12288 + sgo, &lds[(NBO) + 12288u + ldso]);                  \
    }

    // prologue: stage tiles 0 and 1 into buffers 0 and 1
    STAGE(0, 0u)
    STAGE(1, 16384u)

    // anti-lockstep: delay one block of each co-resident pair (b, b+256)
    // by ~1920 cycles (half a tile period) AFTER its prefetch is in flight.
    if ((blockIdx.x >> 8) & 1) __builtin_amdgcn_s_sleep(30);

    // main loop: queue at top of step t = [stage(t):4, stage(t+1):4]
    //   -> vmcnt(4) retires stage(t). Buffer o2 (stage target) was last
    //   read at compute(t-1), retired by this step's barrier.
    unsigned o0 = 0u, o1 = 16384u, o2 = 32768u;
    for (int t = 0; t < NTILES - 2; ++t) {
        asm volatile("s_waitcnt vmcnt(4)" ::: "memory");
        __builtin_amdgcn_s_barrier();
        __builtin_amdgcn_sched_barrier(0);
        STAGE(t + 2, o2)
        PAIR(o0, 0u, t * 4)
        PAIR(o0, 8192u, t * 4 + 2)
        const unsigned tmp = o0; o0 = o1; o1 = o2; o2 = tmp;
    }
    // t = 30: queue = [stage(30):4, stage(31):4]; no new stage
    asm volatile("s_waitcnt vmcnt(4)" ::: "memory");
    __builtin_amdgcn_s_barrier();
    __builtin_amdgcn_sched_barrier(0);
    PAIR(o0, 0u, 120)
    PAIR(o0, 8192u, 122)
    { const unsigned tmp = o0; o0 = o1; o1 = o2; o2 = tmp; }
    // t = 31: queue = [stage(31):4]
    asm volatile("s_waitcnt vmcnt(0)" ::: "memory");
    __builtin_amdgcn_s_barrier();
    __builtin_amdgcn_sched_barrier(0);
    PAIR(o0, 0u, 124)
    PAIR(o0, 8192u, 126)

#undef STAGE
#undef PAIR

    // unpack (score, code) and cross-lane top-2 merge over 16 code-lanes
    const int cb_base = split * (NC / NSPLIT);
    float v1[4][4], v2[4][4];
    int   c1[4][4], c2[4][4];
#pragma unroll
    for (int tt = 0; tt < 4; ++tt)
#pragma unroll
        for (int r = 0; r < 4; ++r) {
            int j1 = 127 - (int)(__float_as_uint(b1[tt][r]) & 127u);
            int j2 = 127 - (int)(__float_as_uint(b2[tt][r]) & 127u);
            v1[tt][r] = b1[tt][r]; c1[tt][r] = cb_base + j1 * 16 + n;
            v2[tt][r] = b2[tt][r]; c2[tt][r] = cb_base + j2 * 16 + n;
        }

#pragma unroll
    for (int tt = 0; tt < 4; ++tt)
#pragma unroll
        for (int r = 0; r < 4; ++r) {
#pragma unroll
            for (int off = 1; off < 16; off <<= 1) {
                float ob1 = __shfl_xor(v1[tt][r], off, 64);
                int   oi1 = __shfl_xor(c1[tt][r], off, 64);
                float ob2 = __shfl_xor(v2[tt][r], off, 64);
                int   oi2 = __shfl_xor(c2[tt][r], off, 64);
                bool gt = (ob1 > v1[tt][r]) ||
                          (ob1 == v1[tt][r] && oi1 < c1[tt][r]);
                float ls = gt ? v1[tt][r] : ob1;
                int   li = gt ? c1[tt][r] : oi1;
                float ws_ = gt ? ob2 : v2[tt][r];
                int   wi = gt ? oi2 : c2[tt][r];
                bool s2 = (ls > ws_) || (ls == ws_ && li < wi);
                v2[tt][r] = s2 ? ls : ws_;
                c2[tt][r] = s2 ? li : wi;
                v1[tt][r] = gt ? ob1 : v1[tt][r];
                c1[tt][r] = gt ? oi1 : c1[tt][r];
            }
        }

    // each wave owns its 64 tokens exclusively -> direct store, no LDS merge
    if (n == 0) {
#pragma unroll
        for (int tt = 0; tt < 4; ++tt)
#pragma unroll
            for (int r = 0; r < 4; ++r) {
                const int token = t0 + w * 64 + tt * 16 + quad * 4 + r;
                const size_t o = (size_t)split * NT + token;
                sb1[o] = v1[tt][r]; si1[o] = c1[tt][r];
                sb2[o] = v2[tt][r]; si2[o] = c2[tt][r];
            }
    }
}

// ---- combine: wave-cooperative merge + distributed exact rescore ----
// grid 512 x 256; each wave owns 8 tokens; within a token's 8-lane group,
// lane cl holds split cl's (top1, top2). shfl_xor reduces stay inside the
// 8-lane group for offsets 1,2,4.
__global__ __launch_bounds__(256) void lfq_combine(
    const float* __restrict__ sb1, const float* __restrict__ sb2,
    const int* __restrict__ si1, const int* __restrict__ si2,
    const float* __restrict__ xf, const float* __restrict__ cf,
    float* __restrict__ out, int out_size)
{
    const int lane = threadIdx.x & 63;
    const int wv   = threadIdx.x >> 6;
    const int g    = lane >> 3;        // token sub-index within wave, 0..7
    const int cl   = lane & 7;         // split index, 0..7
    const int t    = (blockIdx.x * 4 + wv) * 8 + g;

    const size_t o = (size_t)cl * NT + t;
    const float va = sb1[o]; const int ia = si1[o];
    const float vb = sb2[o]; const int ib = si2[o];

    // lane-local best (lowest-id tiebreak), then 8-lane group max
    bool lgt = (vb > va) || (vb == va && ib < ia);
    float m  = lgt ? vb : va;
    int   mi = lgt ? ib : ia;
#pragma unroll
    for (int off = 1; off < 8; off <<= 1) {
        float om = __shfl_xor(m, off, 64);
        int   oi = __shfl_xor(mi, off, 64);
        if (om > m || (om == m && oi < mi)) { m = om; mi = oi; }
    }
    const float A1 = m;
    const int   I1 = mi;

    const bool ba = (va >= A1 - MARGIN);
    const bool bb_ = (vb >= A1 - MARGIN);
    int cnt = (ba ? 1 : 0) + (bb_ ? 1 : 0);
#pragma unroll
    for (int off = 1; off < 8; off <<= 1)
        cnt += __shfl_xor(cnt, off, 64);

    int bi = I1;
    if (cnt > 1) {
        float sa = -__builtin_inff(), sb_ = -__builtin_inff();
        if (ba)  sa  = exact_dot_g(xf, cf, t, ia);
        if (bb_) sb_ = exact_dot_g(xf, cf, t, ib);
        bool g2 = (sb_ > sa) || (sb_ == sa && ib < ia);
        float bs = g2 ? sb_ : sa;
        int  bid = g2 ? ib : ia;
#pragma unroll
        for (int off = 1; off < 8; off <<= 1) {
            float os = __shfl_xor(bs, off, 64);
            int   oi = __shfl_xor(bid, off, 64);
            if (os > bs || (os == bs && oi < bid)) { bs = os; bid = oi; }
        }
        bi = bid;
    }
    if (cl == 0) out[t] = (float)bi;
    if (blockIdx.x == 0 && threadIdx.x == 0 && out_size > NT) out[NT] = 0.0f;
}

// ------------- fallback: round-3 exact fp32 kernel (tiny ws) -------------
__global__ __launch_bounds__(512) void lfq_fp32_argmax(
    const float* __restrict__ xf, const float* __restrict__ cf,
    float* __restrict__ out, int out_size)
{
    const int tid = threadIdx.x;
    const int w   = tid >> 6;
    const int tok = tid & 63;
    const int t0  = blockIdx.x * 64;
    __shared__ float s_sc[8][64];
    __shared__ int   s_ix[8][64];

    float4 xr[32];
    const float4* xrow = (const float4*)(xf + (size_t)(t0 + tok) * ND);
#pragma unroll
    for (int i = 0; i < 32; ++i) xr[i] = xrow[i];

    float bs = -__builtin_inff();
    int   bi = 0;
    const int c_begin = w * (NC / 8);
    for (int c = c_begin; c < c_begin + NC / 8; ++c) {
        float s = exact_dot(xr, cf, c);
        if (s > bs) { bs = s; bi = c; }
    }
    s_sc[w][tok] = bs; s_ix[w][tok] = bi;
    __syncthreads();
    if (tid < 64) {
        float bsf = s_sc[0][tid]; int bif = s_ix[0][tid];
#pragma unroll
        for (int ww = 1; ww < 8; ++ww) {
            float s2 = s_sc[ww][tid]; int ii = s_ix[ww][tid];
            if (s2 > bsf || (s2 == bsf && ii < bif)) { bsf = s2; bif = ii; }
        }
        out[t0 + tid] = (float)bif;
    }
    if (blockIdx.x == 0 && tid == 0 && out_size > NT) out[NT] = 0.0f;
}

extern "C" void kernel_launch(void* const* d_in, const int* in_sizes, int n_in,
                              void* d_out, int out_size, void* d_ws, size_t ws_size,
                              hipStream_t stream) {
    const float* x  = (const float*)d_in[0];
    const float* cb = (const float*)d_in[1];
    float* out = (float*)d_out;

    // ws: cbs 4.19MB (hi-only swizzled tile images) | sb1/sb2/si1/si2 512KB ea
    const size_t NCE = (size_t)NC * ND;          // 2,097,152 codebook elements
    const size_t NEED = NCE * 2 + (size_t)NT * NSPLIT * 4 * 4;
    if (ws_size >= NEED) {
        char* ws = (char*)d_ws;
        unsigned short* cbs = (unsigned short*)ws;
        char* sp = ws + NCE * 2;
        float* sb1 = (float*)sp;
        float* sb2 = (float*)(sp + (size_t)NT * NSPLIT * 4);
        int*   si1 = (int*)  (sp + (size_t)NT * NSPLIT * 8);
        int*   si2 = (int*)  (sp + (size_t)NT * NSPLIT * 12);

        lfq_convert_cb<<<dim3(1024), dim3(256), 0, stream>>>(
            (const float4*)cb, cbs);
        lfq_stage1<<<dim3((NT / 256) * NSPLIT), dim3(256), 0, stream>>>(
            x, cbs, sb1, sb2, si1, si2);
        lfq_combine<<<dim3(NT / 32), dim3(256), 0, stream>>>(
            sb1, sb2, si1, si2, x, cb, out, out_size);
    } else {
        lfq_fp32_argmax<<<dim3(NT / 64), dim3(512), 0, stream>>>(x, cb, out, out_size);
    }
}

// Round 8
// 156.766 us; speedup vs baseline: 1.0518x; 1.0518x over previous
//
#include <hip/hip_runtime.h>
#include <hip/hip_bf16.h>

// LFQ argmax, round 22: delete the LDS machine -- barrier-free L2-resident B.
// r15-r21: seven structural variations all pinned at ~101-104us; invariant
// was the barrier-synced LDS staging loop (2-phase ceiling, m233). The
// B-slice per split is 512KB = L2-resident on its XCD (grid already
// XCD-affine via split=blockIdx&7); the 16KB working tile even fits L1.
// Changes:
//  - stage1 reads B fragments DIRECTLY from global into registers: no LDS,
//    no __syncthreads, no gl2lds, no stagger. Waves free-run; compiler's
//    fine vmcnt(N) pipelining hides ~200cyc L2 latency under the previous
//    pair's 32-MFMA burst. Double-buffered q regs (qA/qB named, unroll 2).
//  - cbs image redefined fragment-coalesced (no LDS -> no bank-conflict
//    swizzle needed): fragment load = contiguous 1KB, lane l at byte l*16.
//    Element (c,d): split=c>>11, cl=c&2047, pair=cl>>5, sp=(cl>>4)&1,
//    n=cl&15, k=d>>5, quad=(d>>3)&3, j=d&7 ->
//    byte = split*524288 + pair*8192 + sp*4096 + k*1024 + quad*256 + n*16 + 2j.
//    Fragment content per lane is IDENTICAL to r20 (code row n, dim chunk
//    quad+4k) -> MFMA/screen/merge/combine numerics untouched.
// Canary: SQ_LDS_BANK_CONFLICT ~0, LDS_Block_Size 0, FETCH ~35MB.
// Numerics unchanged (validated r15-r21): 1-term bf16 screen, 7-bit j-pack
// top-2 per split, MARGIN 0.4 exact rescore.
#define NT 16384
#define ND 128
#define NC 16384
#define NSPLIT 8
#define MARGIN 0.4f       // >= 3x worst pairwise 1-term bf16 comparison error

typedef __bf16 bf16x8 __attribute__((ext_vector_type(8)));
typedef unsigned short u16x8 __attribute__((ext_vector_type(8)));
typedef float f32x4 __attribute__((ext_vector_type(4)));

#define MF __builtin_amdgcn_mfma_f32_16x16x32_bf16

static __device__ __forceinline__ unsigned short f2bf(float f) {
    unsigned u = __float_as_uint(f);
    return (unsigned short)((u + 0x7FFFu + ((u >> 16) & 1u)) >> 16);
}
static __device__ __forceinline__ float bf2f(unsigned short u) {
    return __uint_as_float(((unsigned)u) << 16);
}
static __device__ __forceinline__ bf16x8 u2b(u16x8 u) {
    return __builtin_bit_cast(bf16x8, u);
}

// ---- codebook fp32 -> bf16 hi, fragment-coalesced image ----
// One thread per (code, 8-dim chunk): 32B contiguous read, 16B store.
__global__ __launch_bounds__(256) void lfq_convert_cb(
    const float4* __restrict__ cb4, unsigned short* __restrict__ cbs)
{
    const unsigned i = blockIdx.x * 256 + threadIdx.x;   // 0..262143
    const unsigned c  = i >> 4;          // code 0..16383
    const unsigned k8 = i & 15u;         // dim chunk (d0 = k8*8)
    const float4 v0 = cb4[i * 2];
    const float4 v1 = cb4[i * 2 + 1];
    const unsigned split = c >> 11;
    const unsigned cl    = c & 2047u;
    const unsigned pair  = cl >> 5;
    const unsigned sp    = (cl >> 4) & 1u;
    const unsigned n     = cl & 15u;
    const unsigned k     = k8 >> 2;
    const unsigned quad  = k8 & 3u;
    // byte offset / 2 = u16 index
    const unsigned idx = split * 262144u + pair * 4096u + sp * 2048u +
                         k * 512u + quad * 128u + n * 8u;
    u16x8 h;
    h[0] = f2bf(v0.x); h[1] = f2bf(v0.y); h[2] = f2bf(v0.z); h[3] = f2bf(v0.w);
    h[4] = f2bf(v1.x); h[5] = f2bf(v1.y); h[6] = f2bf(v1.z); h[7] = f2bf(v1.w);
    *(u16x8*)(cbs + idx) = h;
}

// exact fp32 dot, register-preloaded x (fallback kernel)
static __device__ __forceinline__ float exact_dot(
    const float4* __restrict__ xr4, const float* __restrict__ cf, int cidx)
{
    const float4* cr = (const float4*)(cf + (size_t)cidx * ND);
    float a0 = 0.f, a1 = 0.f, a2 = 0.f, a3 = 0.f;
#pragma unroll
    for (int i = 0; i < 32; i += 4) {
        float4 x0 = xr4[i+0], x1 = xr4[i+1], x2 = xr4[i+2], x3 = xr4[i+3];
        float4 c0 = cr[i+0],  c1 = cr[i+1],  c2 = cr[i+2],  c3 = cr[i+3];
        a0 += x0.x*c0.x + x0.y*c0.y + x0.z*c0.z + x0.w*c0.w;
        a1 += x1.x*c1.x + x1.y*c1.y + x1.z*c1.z + x1.w*c1.w;
        a2 += x2.x*c2.x + x2.y*c2.y + x2.z*c2.z + x2.w*c2.w;
        a3 += x3.x*c3.x + x3.y*c3.y + x3.z*c3.z + x3.w*c3.w;
    }
    return (a0 + a1) + (a2 + a3);
}

// exact fp32 dot, both operands from global (combine kernel)
static __device__ __forceinline__ float exact_dot_g(
    const float* __restrict__ xf, const float* __restrict__ cf,
    int token, int cidx)
{
    const float4* xr = (const float4*)(xf + (size_t)token * ND);
    const float4* cr = (const float4*)(cf + (size_t)cidx * ND);
    float a0 = 0.f, a1 = 0.f, a2 = 0.f, a3 = 0.f;
#pragma unroll
    for (int i = 0; i < 32; i += 4) {
        float4 x0 = xr[i+0], x1 = xr[i+1], x2 = xr[i+2], x3 = xr[i+3];
        float4 c0 = cr[i+0], c1 = cr[i+1], c2 = cr[i+2], c3 = cr[i+3];
        a0 += x0.x*c0.x + x0.y*c0.y + x0.z*c0.z + x0.w*c0.w;
        a1 += x1.x*c1.x + x1.y*c1.y + x1.z*c1.z + x1.w*c1.w;
        a2 += x2.x*c2.x + x2.y*c2.y + x2.z*c2.z + x2.w*c2.w;
        a3 += x3.x*c3.x + x3.y*c3.y + x3.z*c3.z + x3.w*c3.w;
    }
    return (a0 + a1) + (a2 + a3);
}

static __device__ __forceinline__ void top2_upd(
    const f32x4& a, float* b1r, float* b2r, unsigned pk)
{
#pragma unroll
    for (int r4 = 0; r4 < 4; ++r4) {
        float p = __uint_as_float((__float_as_uint(a[r4]) & 0xFFFFFF80u) | pk);
        b2r[r4] = __builtin_amdgcn_fmed3f(p, b1r[r4], b2r[r4]);
        b1r[r4] = fmaxf(p, b1r[r4]);
    }
}

// ---- stage 1: grid 512 = 64 token-blocks(256 tok) x 8 splits ----
// Block: 256 threads = 4 waves; wave w covers tokens t0+w*64..+63 (tt=4).
// B fragments stream from global (L2/L1-resident) -- NO LDS, NO barriers.
__global__ __launch_bounds__(256)
__attribute__((amdgpu_waves_per_eu(2, 2)))
void lfq_stage1(
    const float* __restrict__ xf, const unsigned short* __restrict__ cbs,
    float* __restrict__ sb1, float* __restrict__ sb2,
    int* __restrict__ si1, int* __restrict__ si2)
{
    const int split = blockIdx.x & 7;
    const int tb    = blockIdx.x >> 3;
    const int t0    = tb * 256;
    const int tid   = threadIdx.x;
    const int w     = tid >> 6;       // wave id = token-group, 0..3
    const int lane  = tid & 63;
    const int n     = lane & 15;
    const int quad  = lane >> 4;

    // A fragments: tokens t0 + w*64 + tt*16 + n, tt=0..3; fp32 -> bf16 (RN).
    bf16x8 ah[4][4];
#pragma unroll
    for (int tt = 0; tt < 4; ++tt) {
        const float* xr = xf + (size_t)(t0 + w * 64 + tt * 16 + n) * ND + quad * 8;
#pragma unroll
        for (int kk = 0; kk < 4; ++kk) {
            float4 v0 = *(const float4*)(xr + kk * 32);
            float4 v1 = *(const float4*)(xr + kk * 32 + 4);
            u16x8 hu;
            hu[0] = f2bf(v0.x);
            hu[1] = f2bf(v0.y);
            hu[2] = f2bf(v0.z);
            hu[3] = f2bf(v0.w);
            hu[4] = f2bf(v1.x);
            hu[5] = f2bf(v1.y);
            hu[6] = f2bf(v1.z);
            hu[7] = f2bf(v1.w);
            ah[tt][kk] = u2b(hu);
        }
    }

    float b1[4][4], b2[4][4];
#pragma unroll
    for (int tt = 0; tt < 4; ++tt)
#pragma unroll
        for (int r = 0; r < 4; ++r) { b1[tt][r] = -3.0e38f; b2[tt][r] = -3.0e38f; }

    // per-lane fragment base: lane l reads byte l*16 of each 1KB block
    const unsigned char* gp =
        (const unsigned char*)cbs + (size_t)split * 524288u +
        (unsigned)lane * 16u;

    const f32x4 zq = {0.f, 0.f, 0.f, 0.f};

    // load the 8 fragments of pair p (two 16-code subsets x 4 K-fragments)
#define LOADPAIR(Q0,Q1,Q2,Q3,Q4,Q5,Q6,Q7, G)                                   \
    Q0 = *(const bf16x8*)((G));                                                \
    Q1 = *(const bf16x8*)((G) + 1024);                                         \
    Q2 = *(const bf16x8*)((G) + 2048);                                         \
    Q3 = *(const bf16x8*)((G) + 3072);                                         \
    Q4 = *(const bf16x8*)((G) + 4096);                                         \
    Q5 = *(const bf16x8*)((G) + 5120);                                         \
    Q6 = *(const bf16x8*)((G) + 6144);                                         \
    Q7 = *(const bf16x8*)((G) + 7168);

    // compute pair p: 32 MFMAs over 8 chains, then 8 top-2 screens
#define COMPUTE(Q0,Q1,Q2,Q3,Q4,Q5,Q6,Q7, P)                                    \
    {                                                                          \
        f32x4 aA0, aA1, aA2, aA3, aB0, aB1, aB2, aB3;                          \
        __builtin_amdgcn_s_setprio(1);                                         \
        aA0 = MF(ah[0][0], Q0, zq,  0,0,0);                                    \
        aA1 = MF(ah[1][0], Q0, zq,  0,0,0);                                    \
        aA2 = MF(ah[2][0], Q0, zq,  0,0,0);                                    \
        aA3 = MF(ah[3][0], Q0, zq,  0,0,0);                                    \
        aB0 = MF(ah[0][0], Q4, zq,  0,0,0);                                    \
        aB1 = MF(ah[1][0], Q4, zq,  0,0,0);                                    \
        aB2 = MF(ah[2][0], Q4, zq,  0,0,0);                                    \
        aB3 = MF(ah[3][0], Q4, zq,  0,0,0);                                    \
        aA0 = MF(ah[0][1], Q1, aA0, 0,0,0);                                    \
        aA1 = MF(ah[1][1], Q1, aA1, 0,0,0);                                    \
        aA2 = MF(ah[2][1], Q1, aA2, 0,0,0);                                    \
        aA3 = MF(ah[3][1], Q1, aA3, 0,0,0);                                    \
        aB0 = MF(ah[0][1], Q5, aB0, 0,0,0);                                    \
        aB1 = MF(ah[1][1], Q5, aB1, 0,0,0);                                    \
        aB2 = MF(ah[2][1], Q5, aB2, 0,0,0);                                    \
        aB3 = MF(ah[3][1], Q5, aB3, 0,0,0);                                    \
        aA0 = MF(ah[0][2], Q2, aA0, 0,0,0);                                    \
        aA1 = MF(ah[1][2], Q2, aA1, 0,0,0);                                    \
        aA2 = MF(ah[2][2], Q2, aA2, 0,0,0);                                    \
        aA3 = MF(ah[3][2], Q2, aA3, 0,0,0);                                    \
        aB0 = MF(ah[0][2], Q6, aB0, 0,0,0);                                    \
        aB1 = MF(ah[1][2], Q6, aB1, 0,0,0);                                    \
        aB2 = MF(ah[2][2], Q6, aB2, 0,0,0);                                    \
        aB3 = MF(ah[3][2], Q6, aB3, 0,0,0);                                    \
        aA0 = MF(ah[0][3], Q3, aA0, 0,0,0);                                    \
        aA1 = MF(ah[1][3], Q3, aA1, 0,0,0);                                    \
        aA2 = MF(ah[2][3], Q3, aA2, 0,0,0);                                    \
        aA3 = MF(ah[3][3], Q3, aA3, 0,0,0);                                    \
        aB0 = MF(ah[0][3], Q7, aB0, 0,0,0);                                    \
        aB1 = MF(ah[1][3], Q7, aB1, 0,0,0);                                    \
        aB2 = MF(ah[2][3], Q7, aB2, 0,0,0);                                    \
        aB3 = MF(ah[3][3], Q7, aB3, 0,0,0);                                    \
        __builtin_amdgcn_s_setprio(0);                                         \
        const unsigned pkA = (unsigned)(127 - (P) * 2);                        \
        const unsigned pkB = (unsigned)(127 - (P) * 2 - 1);                    \
        top2_upd(aA0, b1[0], b2[0], pkA);                                      \
        top2_upd(aA1, b1[1], b2[1], pkA);                                      \
        top2_upd(aA2, b1[2], b2[2], pkA);                                      \
        top2_upd(aA3, b1[3], b2[3], pkA);                                      \
        top2_upd(aB0, b1[0], b2[0], pkB);                                      \
        top2_upd(aB1, b1[1], b2[1], pkB);                                      \
        top2_upd(aB2, b1[2], b2[2], pkB);                                      \
        top2_upd(aB3, b1[3], b2[3], pkB);                                      \
    }

    bf16x8 qa0, qa1, qa2, qa3, qa4, qa5, qa6, qa7;
    bf16x8 qb0, qb1, qb2, qb3, qb4, qb5, qb6, qb7;

    // prologue: load pair 0
    LOADPAIR(qa0,qa1,qa2,qa3,qa4,qa5,qa6,qa7, gp)

    // 64 pairs total; unroll 2 (named double buffer, rule #20)
    for (int p = 0; p < 62; p += 2) {
        LOADPAIR(qb0,qb1,qb2,qb3,qb4,qb5,qb6,qb7, gp + (p + 1) * 8192)
        COMPUTE (qa0,qa1,qa2,qa3,qa4,qa5,qa6,qa7, p)
        LOADPAIR(qa0,qa1,qa2,qa3,qa4,qa5,qa6,qa7, gp + (p + 2) * 8192)
        COMPUTE (qb0,qb1,qb2,qb3,qb4,qb5,qb6,qb7, p + 1)
    }
    LOADPAIR(qb0,qb1,qb2,qb3,qb4,qb5,qb6,qb7, gp + 63 * 8192)
    COMPUTE (qa0,qa1,qa2,qa3,qa4,qa5,qa6,qa7, 62)
    COMPUTE (qb0,qb1,qb2,qb3,qb4,qb5,qb6,qb7, 63)

#undef LOADPAIR
#undef COMPUTE

    // unpack (score, code) and cross-lane top-2 merge over 16 code-lanes
    const int cb_base = split * (NC / NSPLIT);
    float v1[4][4], v2[4][4];
    int   c1[4][4], c2[4][4];
#pragma unroll
    for (int tt = 0; tt < 4; ++tt)
#pragma unroll
        for (int r = 0; r < 4; ++r) {
            int j1 = 127 - (int)(__float_as_uint(b1[tt][r]) & 127u);
            int j2 = 127 - (int)(__float_as_uint(b2[tt][r]) & 127u);
            v1[tt][r] = b1[tt][r]; c1[tt][r] = cb_base + j1 * 16 + n;
            v2[tt][r] = b2[tt][r]; c2[tt][r] = cb_base + j2 * 16 + n;
        }

#pragma unroll
    for (int tt = 0; tt < 4; ++tt)
#pragma unroll
        for (int r = 0; r < 4; ++r) {
#pragma unroll
            for (int off = 1; off < 16; off <<= 1) {
                float ob1 = __shfl_xor(v1[tt][r], off, 64);
                int   oi1 = __shfl_xor(c1[tt][r], off, 64);
                float ob2 = __shfl_xor(v2[tt][r], off, 64);
                int   oi2 = __shfl_xor(c2[tt][r], off, 64);
                bool gt = (ob1 > v1[tt][r]) ||
                          (ob1 == v1[tt][r] && oi1 < c1[tt][r]);
                float ls = gt ? v1[tt][r] : ob1;
                int   li = gt ? c1[tt][r] : oi1;
                float ws_ = gt ? ob2 : v2[tt][r];
                int   wi = gt ? oi2 : c2[tt][r];
                bool s2 = (ls > ws_) || (ls == ws_ && li < wi);
                v2[tt][r] = s2 ? ls : ws_;
                c2[tt][r] = s2 ? li : wi;
                v1[tt][r] = gt ? ob1 : v1[tt][r];
                c1[tt][r] = gt ? oi1 : c1[tt][r];
            }
        }

    // each wave owns its 64 tokens exclusively -> direct store
    if (n == 0) {
#pragma unroll
        for (int tt = 0; tt < 4; ++tt)
#pragma unroll
            for (int r = 0; r < 4; ++r) {
                const int token = t0 + w * 64 + tt * 16 + quad * 4 + r;
                const size_t o = (size_t)split * NT + token;
                sb1[o] = v1[tt][r]; si1[o] = c1[tt][r];
                sb2[o] = v2[tt][r]; si2[o] = c2[tt][r];
            }
    }
}

// ---- combine: wave-cooperative merge + distributed exact rescore ----
__global__ __launch_bounds__(256) void lfq_combine(
    const float* __restrict__ sb1, const float* __restrict__ sb2,
    const int* __restrict__ si1, const int* __restrict__ si2,
    const float* __restrict__ xf, const float* __restrict__ cf,
    float* __restrict__ out, int out_size)
{
    const int lane = threadIdx.x & 63;
    const int wv   = threadIdx.x >> 6;
    const int g    = lane >> 3;        // token sub-index within wave, 0..7
    const int cl   = lane & 7;         // split index, 0..7
    const int t    = (blockIdx.x * 4 + wv) * 8 + g;

    const size_t o = (size_t)cl * NT + t;
    const float va = sb1[o]; const int ia = si1[o];
    const float vb = sb2[o]; const int ib = si2[o];

    // lane-local best (lowest-id tiebreak), then 8-lane group max
    bool lgt = (vb > va) || (vb == va && ib < ia);
    float m  = lgt ? vb : va;
    int   mi = lgt ? ib : ia;
#pragma unroll
    for (int off = 1; off < 8; off <<= 1) {
        float om = __shfl_xor(m, off, 64);
        int   oi = __shfl_xor(mi, off, 64);
        if (om > m || (om == m && oi < mi)) { m = om; mi = oi; }
    }
    const float A1 = m;
    const int   I1 = mi;

    const bool ba = (va >= A1 - MARGIN);
    const bool bb_ = (vb >= A1 - MARGIN);
    int cnt = (ba ? 1 : 0) + (bb_ ? 1 : 0);
#pragma unroll
    for (int off = 1; off < 8; off <<= 1)
        cnt += __shfl_xor(cnt, off, 64);

    int bi = I1;
    if (cnt > 1) {
        float sa = -__builtin_inff(), sb_ = -__builtin_inff();
        if (ba)  sa  = exact_dot_g(xf, cf, t, ia);
        if (bb_) sb_ = exact_dot_g(xf, cf, t, ib);
        bool g2 = (sb_ > sa) || (sb_ == sa && ib < ia);
        float bs = g2 ? sb_ : sa;
        int  bid = g2 ? ib : ia;
#pragma unroll
        for (int off = 1; off < 8; off <<= 1) {
            float os = __shfl_xor(bs, off, 64);
            int   oi = __shfl_xor(bid, off, 64);
            if (os > bs || (os == bs && oi < bid)) { bs = os; bid = oi; }
        }
        bi = bid;
    }
    if (cl == 0) out[t] = (float)bi;
    if (blockIdx.x == 0 && threadIdx.x == 0 && out_size > NT) out[NT] = 0.0f;
}

// ------------- fallback: round-3 exact fp32 kernel (tiny ws) -------------
__global__ __launch_bounds__(512) void lfq_fp32_argmax(
    const float* __restrict__ xf, const float* __restrict__ cf,
    float* __restrict__ out, int out_size)
{
    const int tid = threadIdx.x;
    const int w   = tid >> 6;
    const int tok = tid & 63;
    const int t0  = blockIdx.x * 64;
    __shared__ float s_sc[8][64];
    __shared__ int   s_ix[8][64];

    float4 xr[32];
    const float4* xrow = (const float4*)(xf + (size_t)(t0 + tok) * ND);
#pragma unroll
    for (int i = 0; i < 32; ++i) xr[i] = xrow[i];

    float bs = -__builtin_inff();
    int   bi = 0;
    const int c_begin = w * (NC / 8);
    for (int c = c_begin; c < c_begin + NC / 8; ++c) {
        float s = exact_dot(xr, cf, c);
        if (s > bs) { bs = s; bi = c; }
    }
    s_sc[w][tok] = bs; s_ix[w][tok] = bi;
    __syncthreads();
    if (tid < 64) {
        float bsf = s_sc[0][tid]; int bif = s_ix[0][tid];
#pragma unroll
        for (int ww = 1; ww < 8; ++ww) {
            float s2 = s_sc[ww][tid]; int ii = s_ix[ww][tid];
            if (s2 > bsf || (s2 == bsf && ii < bif)) { bsf = s2; bif = ii; }
        }
        out[t0 + tid] = (float)bif;
    }
    if (blockIdx.x == 0 && tid == 0 && out_size > NT) out[NT] = 0.0f;
}

extern "C" void kernel_launch(void* const* d_in, const int* in_sizes, int n_in,
                              void* d_out, int out_size, void* d_ws, size_t ws_size,
                              hipStream_t stream) {
    const float* x  = (const float*)d_in[0];
    const float* cb = (const float*)d_in[1];
    float* out = (float*)d_out;

    // ws: cbs 4.19MB (fragment-coalesced image) | sb1/sb2/si1/si2 512KB ea
    const size_t NCE = (size_t)NC * ND;          // 2,097,152 codebook elements
    const size_t NEED = NCE * 2 + (size_t)NT * NSPLIT * 4 * 4;
    if (ws_size >= NEED) {
        char* ws = (char*)d_ws;
        unsigned short* cbs = (unsigned short*)ws;
        char* sp = ws + NCE * 2;
        float* sb1 = (float*)sp;
        float* sb2 = (float*)(sp + (size_t)NT * NSPLIT * 4);
        int*   si1 = (int*)  (sp + (size_t)NT * NSPLIT * 8);
        int*   si2 = (int*)  (sp + (size_t)NT * NSPLIT * 12);

        lfq_convert_cb<<<dim3(1024), dim3(256), 0, stream>>>(
            (const float4*)cb, cbs);
        lfq_stage1<<<dim3((NT / 256) * NSPLIT), dim3(256), 0, stream>>>(
            x, cbs, sb1, sb2, si1, si2);
        lfq_combine<<<dim3(NT / 32), dim3(256), 0, stream>>>(
            sb1, sb2, si1, si2, x, cb, out, out_size);
    } else {
        lfq_fp32_argmax<<<dim3(NT / 64), dim3(512), 0, stream>>>(x, cb, out, out_size);
    }
}